// Round 1
// baseline (1840.593 us; speedup 1.0000x reference)
//
#include <hip/hip_runtime.h>
#include <hip/hip_bf16.h>
#include <math.h>

// Problem constants
#define BATCH 2
#define SEQ   1024
#define HID   2048
#define NH    16
#define NKV   4
#define HEAD  128
#define MROWS (BATCH*SEQ)   // 2048

// ---------------------------------------------------------------------------
// quad (4-lane) sum via DPP quad_perm — VALU pipe, no LDS traffic
// ---------------------------------------------------------------------------
__device__ __forceinline__ float quad_sum(float x) {
    x += __int_as_float(__builtin_amdgcn_mov_dpp(__float_as_int(x), 0xB1, 0xF, 0xF, true)); // xor 1
    x += __int_as_float(__builtin_amdgcn_mov_dpp(__float_as_int(x), 0x4E, 0xF, 0xF, true)); // xor 2
    return x;
}

// ---------------------------------------------------------------------------
// fp32 GEMM, 128x128 tile, BK=16, 256 threads, 8x8 per thread.
// MODE 1: fused QKV (virtual N = 3072 over [wq|wk|wv]) + RoPE epilogue on q,k.
//   column map per thread: n = 4*tx + 64*nn + j  (nn=0 -> d<64, nn=1 -> d>=64)
//   so each thread holds both rotate-half partners of its outputs.
// MODE 0: plain C = A @ W0 (N=2048).
// ---------------------------------------------------------------------------
template<int MODE>
__global__ __launch_bounds__(256, 2)
void gemm_kernel(const float* __restrict__ A,
                 const float* __restrict__ W0,
                 const float* __restrict__ W1,
                 const float* __restrict__ W2,
                 const float* __restrict__ cosp,
                 const float* __restrict__ sinp,
                 float* __restrict__ C0,
                 float* __restrict__ C1,
                 float* __restrict__ C2)
{
    __shared__ float As[16][128];   // transposed: As[k][m]
    __shared__ float Bs[16][128];   // Bs[k][n]

    const int tid = threadIdx.x;
    const int tx  = tid & 15;
    const int ty  = tid >> 4;
    const int m0  = blockIdx.y * 128;
    const int n0  = blockIdx.x * 128;

    const float* W;  float* C;
    int ldw, wc0, ldc, cc0;
    bool rope;
    if (MODE == 0) {
        W = W0; ldw = 2048; wc0 = n0; C = C0; ldc = 2048; cc0 = n0; rope = false;
    } else {
        if (n0 < 2048)      { W = W0; ldw = 2048; wc0 = n0;        C = C0; ldc = 2048; cc0 = n0;        rope = true;  }
        else if (n0 < 2560) { W = W1; ldw = 512;  wc0 = n0 - 2048; C = C1; ldc = 512;  cc0 = n0 - 2048; rope = true;  }
        else                { W = W2; ldw = 512;  wc0 = n0 - 2560; C = C2; ldc = 512;  cc0 = n0 - 2560; rope = false; }
    }

    float acc[8][8];
    #pragma unroll
    for (int i = 0; i < 8; ++i)
        #pragma unroll
        for (int j = 0; j < 8; ++j) acc[i][j] = 0.f;

    for (int kt = 0; kt < 2048/16; ++kt) {
        // stage A-tile (128x16, transposed) + B-tile (16x128)
        #pragma unroll
        for (int it = 0; it < 2; ++it) {
            int fid = tid + 256*it;               // 0..511
            int am  = fid >> 2, akq = fid & 3;    // A: row, k-quad
            float4 av = *(const float4*)&A[(size_t)(m0 + am)*2048 + kt*16 + akq*4];
            As[akq*4+0][am] = av.x;
            As[akq*4+1][am] = av.y;
            As[akq*4+2][am] = av.z;
            As[akq*4+3][am] = av.w;
            int bk = fid >> 5, bn4 = fid & 31;    // B: k-row, n-quad
            float4 bv = *(const float4*)&W[(size_t)(kt*16 + bk)*ldw + wc0 + bn4*4];
            *(float4*)&Bs[bk][bn4*4] = bv;
        }
        __syncthreads();

        #pragma unroll
        for (int kk = 0; kk < 16; ++kk) {
            float a[8], bb[8];
            *(float4*)&a[0]  = *(const float4*)&As[kk][ty*8];
            *(float4*)&a[4]  = *(const float4*)&As[kk][ty*8+4];
            *(float4*)&bb[0] = *(const float4*)&Bs[kk][tx*4];        // nn=0
            *(float4*)&bb[4] = *(const float4*)&Bs[kk][64 + tx*4];   // nn=1
            #pragma unroll
            for (int i = 0; i < 8; ++i)
                #pragma unroll
                for (int j = 0; j < 8; ++j)
                    acc[i][j] = fmaf(a[i], bb[j], acc[i][j]);
        }
        __syncthreads();
    }

    // epilogue
    #pragma unroll
    for (int i = 0; i < 8; ++i) {
        int m = m0 + ty*8 + i;
        if (!rope) {
            float4 o0 = make_float4(acc[i][0], acc[i][1], acc[i][2], acc[i][3]);
            float4 o1 = make_float4(acc[i][4], acc[i][5], acc[i][6], acc[i][7]);
            *(float4*)&C[(size_t)m*ldc + cc0 + tx*4]      = o0;
            *(float4*)&C[(size_t)m*ldc + cc0 + 64 + tx*4] = o1;
        } else {
            int s = m & (SEQ-1);
            float o0[4], o1[4];
            #pragma unroll
            for (int j = 0; j < 4; ++j) {
                int d = tx*4 + j;                 // 0..63 (cc0 is head-aligned)
                float cl = cosp[s*HEAD + d],      sl = sinp[s*HEAD + d];
                float ch = cosp[s*HEAD + d + 64], sh = sinp[s*HEAD + d + 64];
                float lo = acc[i][j], hi = acc[i][4+j];
                o0[j] = lo*cl - hi*sl;            // new[d]    = t[d]*cos - t[d+64]*sin
                o1[j] = hi*ch + lo*sh;            // new[d+64] = t[d+64]*cos + t[d]*sin
            }
            *(float4*)&C[(size_t)m*ldc + cc0 + tx*4]      = *(float4*)o0;
            *(float4*)&C[(size_t)m*ldc + cc0 + 64 + tx*4] = *(float4*)o1;
        }
    }
}

// ---------------------------------------------------------------------------
// fp32 flash attention, causal, GQA (kv = h>>2).
// Block = 128 threads = (rp 0..31) x (g 0..3); each thread owns Q-rows
// rp and rp+32 of a 64-row Q-tile and dim set {4g+16*dd+j}.
// K/V tile 32x128 in LDS row-major; reads ds_read_b128, conflict-free by
// construction (lane addresses differ by 4g floats -> 4 distinct banks).
// Each LDS read feeds 8 FMAs (2 rows x 4 dims).
// ---------------------------------------------------------------------------
__global__ __launch_bounds__(128, 2)
void attn_kernel(const float* __restrict__ q,
                 const float* __restrict__ kbuf,
                 const float* __restrict__ vbuf,
                 float* __restrict__ attn)
{
    __shared__ float Ks[32][128];
    __shared__ float Vs[32][128];

    const int tid = threadIdx.x;
    const int g   = tid & 3;
    const int rp  = tid >> 2;              // 0..31
    const int idx = blockIdx.x;
    const int qt  = 15 - (idx >> 5);       // heavy tiles dispatched first
    const int bh  = idx & 31;
    const int b   = bh >> 4;
    const int h   = bh & 15;
    const int kv  = h >> 2;

    const float scale = 0.08838834764831845f;  // 1/sqrt(128)

    const int rowA = qt*64 + rp;           // sequence positions
    const int rowB = rowA + 32;

    float qr0[32], qr1[32];
    {
        const float* qbA = q + ((size_t)(b*SEQ + rowA))*HID + h*HEAD;
        const float* qbB = q + ((size_t)(b*SEQ + rowB))*HID + h*HEAD;
        #pragma unroll
        for (int dd = 0; dd < 8; ++dd) {
            float4 ta = *(const float4*)&qbA[4*g + 16*dd];
            float4 tb = *(const float4*)&qbB[4*g + 16*dd];
            qr0[dd*4+0] = ta.x*scale; qr0[dd*4+1] = ta.y*scale;
            qr0[dd*4+2] = ta.z*scale; qr0[dd*4+3] = ta.w*scale;
            qr1[dd*4+0] = tb.x*scale; qr1[dd*4+1] = tb.y*scale;
            qr1[dd*4+2] = tb.z*scale; qr1[dd*4+3] = tb.w*scale;
        }
    }

    float acc0[32], acc1[32];
    #pragma unroll
    for (int i = 0; i < 32; ++i) { acc0[i] = 0.f; acc1[i] = 0.f; }
    float m0 = -INFINITY, m1 = -INFINITY, l0 = 0.f, l1 = 0.f;

    const int ntiles = 2*qt + 2;
    for (int kt = 0; kt < ntiles; ++kt) {
        __syncthreads();   // previous tile's LDS reads done
        #pragma unroll
        for (int it = 0; it < 8; ++it) {
            int fid = tid + 128*it;                    // 0..1023
            int c = fid >> 5, d4 = fid & 31;
            size_t ga = ((size_t)(b*SEQ + kt*32 + c))*(NKV*HEAD) + kv*HEAD + d4*4;
            *(float4*)&Ks[c][d4*4] = *(const float4*)&kbuf[ga];
            *(float4*)&Vs[c][d4*4] = *(const float4*)&vbuf[ga];
        }
        __syncthreads();

        // ---- scores: partial dot over this thread's 32 dims, 32 cols ----
        float p0[32], p1[32];
        #pragma unroll
        for (int c = 0; c < 32; ++c) { p0[c] = 0.f; p1[c] = 0.f; }
        #pragma unroll
        for (int dd = 0; dd < 8; ++dd) {
            #pragma unroll
            for (int c = 0; c < 32; ++c) {
                float4 k4 = *(const float4*)&Ks[c][4*g + 16*dd];
                p0[c] = fmaf(qr0[dd*4+0], k4.x, p0[c]);
                p0[c] = fmaf(qr0[dd*4+1], k4.y, p0[c]);
                p0[c] = fmaf(qr0[dd*4+2], k4.z, p0[c]);
                p0[c] = fmaf(qr0[dd*4+3], k4.w, p0[c]);
                p1[c] = fmaf(qr1[dd*4+0], k4.x, p1[c]);
                p1[c] = fmaf(qr1[dd*4+1], k4.y, p1[c]);
                p1[c] = fmaf(qr1[dd*4+2], k4.z, p1[c]);
                p1[c] = fmaf(qr1[dd*4+3], k4.w, p1[c]);
            }
        }
        #pragma unroll
        for (int c = 0; c < 32; ++c) { p0[c] = quad_sum(p0[c]); p1[c] = quad_sum(p1[c]); }

        // ---- causal mask (only possible in the last two tiles) ----
        if (kt >= 2*qt) {
            #pragma unroll
            for (int c = 0; c < 32; ++c) {
                int col = kt*32 + c;
                if (col > rowA) p0[c] = -INFINITY;
                if (col > rowB) p1[c] = -INFINITY;
            }
        }

        // ---- online softmax update ----
        float pm0 = m0, pm1 = m1;
        #pragma unroll
        for (int c = 0; c < 32; ++c) { pm0 = fmaxf(pm0, p0[c]); pm1 = fmaxf(pm1, p1[c]); }
        float corr0 = __expf(m0 - pm0);
        float corr1 = __expf(m1 - pm1);
        m0 = pm0; m1 = pm1;
        float sum0 = 0.f, sum1 = 0.f;
        #pragma unroll
        for (int c = 0; c < 32; ++c) {
            float e0 = __expf(p0[c] - pm0); p0[c] = e0; sum0 += e0;
            float e1 = __expf(p1[c] - pm1); p1[c] = e1; sum1 += e1;
        }
        l0 = l0*corr0 + sum0;
        l1 = l1*corr1 + sum1;
        #pragma unroll
        for (int i = 0; i < 32; ++i) { acc0[i] *= corr0; acc1[i] *= corr1; }

        // ---- PV accumulate ----
        #pragma unroll
        for (int jj = 0; jj < 8; ++jj) {
            #pragma unroll
            for (int c = 0; c < 32; ++c) {
                float4 v4 = *(const float4*)&Vs[c][4*g + 16*jj];
                acc0[jj*4+0] = fmaf(p0[c], v4.x, acc0[jj*4+0]);
                acc0[jj*4+1] = fmaf(p0[c], v4.y, acc0[jj*4+1]);
                acc0[jj*4+2] = fmaf(p0[c], v4.z, acc0[jj*4+2]);
                acc0[jj*4+3] = fmaf(p0[c], v4.w, acc0[jj*4+3]);
                acc1[jj*4+0] = fmaf(p1[c], v4.x, acc1[jj*4+0]);
                acc1[jj*4+1] = fmaf(p1[c], v4.y, acc1[jj*4+1]);
                acc1[jj*4+2] = fmaf(p1[c], v4.z, acc1[jj*4+2]);
                acc1[jj*4+3] = fmaf(p1[c], v4.w, acc1[jj*4+3]);
            }
        }
    }

    const float inv0 = 1.f / l0;
    const float inv1 = 1.f / l1;
    const size_t obA = ((size_t)(b*SEQ + rowA))*HID + h*HEAD;
    const size_t obB = ((size_t)(b*SEQ + rowB))*HID + h*HEAD;
    #pragma unroll
    for (int jj = 0; jj < 8; ++jj) {
        float4 oA = make_float4(acc0[jj*4+0]*inv0, acc0[jj*4+1]*inv0,
                                acc0[jj*4+2]*inv0, acc0[jj*4+3]*inv0);
        float4 oB = make_float4(acc1[jj*4+0]*inv1, acc1[jj*4+1]*inv1,
                                acc1[jj*4+2]*inv1, acc1[jj*4+3]*inv1);
        *(float4*)&attn[obA + 4*g + 16*jj] = oA;
        *(float4*)&attn[obB + 4*g + 16*jj] = oB;
    }
}

// ---------------------------------------------------------------------------
extern "C" void kernel_launch(void* const* d_in, const int* in_sizes, int n_in,
                              void* d_out, int out_size, void* d_ws, size_t ws_size,
                              hipStream_t stream)
{
    const float* x    = (const float*)d_in[0];
    const float* cosp = (const float*)d_in[1];
    const float* sinp = (const float*)d_in[2];
    const float* wq   = (const float*)d_in[3];
    const float* wk   = (const float*)d_in[4];
    const float* wv   = (const float*)d_in[5];
    const float* wo   = (const float*)d_in[6];
    float* out = (float*)d_out;

    // workspace: q (16MB) | k (4MB) | v (4MB) | attn (16MB) = 40MB
    float* qb   = (float*)d_ws;
    float* kb   = qb + (size_t)MROWS*HID;
    float* vb   = kb + (size_t)MROWS*(NKV*HEAD);
    float* atnb = vb + (size_t)MROWS*(NKV*HEAD);

    // fused QKV projection + RoPE  (virtual N = 3072)
    gemm_kernel<1><<<dim3(24, 16), 256, 0, stream>>>(
        x, wq, wk, wv, cosp, sinp, qb, kb, vb);

    // causal GQA flash attention
    attn_kernel<<<dim3(512), 128, 0, stream>>>(qb, kb, vb, atnb);

    // output projection
    gemm_kernel<0><<<dim3(16, 16), 256, 0, stream>>>(
        atnb, wo, nullptr, nullptr, nullptr, nullptr, out, nullptr, nullptr);
}

// Round 3
// 224.782 us; speedup vs baseline: 8.1884x; 8.1884x over previous
//
#include <hip/hip_runtime.h>
#include <hip/hip_bf16.h>
#include <math.h>
#include <stdint.h>

// Problem constants
#define BATCH 2
#define SEQ   1024
#define HID   2048
#define NH    16
#define NKV   4
#define HEAD  128
#define MROWS (BATCH*SEQ)      // 2048
#define QSC   0.08838834764831845f   // 1/sqrt(128), folded into q at epilogue

typedef _Float16 f16;
typedef _Float16 f16x8 __attribute__((ext_vector_type(8)));
typedef __fp16   h16x2 __attribute__((ext_vector_type(2)));   // cvt_pkrtz return type
typedef float    f32x4 __attribute__((ext_vector_type(4)));

// ---------------------------------------------------------------------------
// helpers
// ---------------------------------------------------------------------------
__device__ __forceinline__ void glds16(const void* g, void* l) {
    // async global->LDS, 16B per lane; LDS dest = wave-uniform base + lane*16
    __builtin_amdgcn_global_load_lds(
        (const __attribute__((address_space(1))) void*)g,
        (__attribute__((address_space(3))) void*)l, 16, 0, 0);
}

__device__ __forceinline__ f32x4 mfma16(f16x8 a, f16x8 b, f32x4 c) {
    return __builtin_amdgcn_mfma_f32_16x16x32_f16(a, b, c, 0, 0, 0);
}

// ---------------------------------------------------------------------------
// fp32 -> fp16 elementwise (x)
// ---------------------------------------------------------------------------
__global__ __launch_bounds__(256)
void cvt_f32_f16(const float* __restrict__ in, f16* __restrict__ out) {
    int i = blockIdx.x * 256 + threadIdx.x;
    float4 v = ((const float4*)in)[i];
    union { ushort4 u; f16 h[4]; } o;
    o.h[0] = (f16)v.x; o.h[1] = (f16)v.y; o.h[2] = (f16)v.z; o.h[3] = (f16)v.w;
    ((ushort4*)out)[i] = o.u;
}

// ---------------------------------------------------------------------------
// W[k][n] fp32 (virtual concat over up to 3 sources) -> Wt[n][k] fp16
// 64x64 tiles via padded LDS. Region boundaries are 64-multiples.
// ---------------------------------------------------------------------------
__global__ __launch_bounds__(256)
void transW(const float* __restrict__ w0, const float* __restrict__ w1,
            const float* __restrict__ w2, f16* __restrict__ out,
            int c1, int c2, int ld0, int ld1, int ld2) {
    __shared__ float t[64][65];
    const int n0 = blockIdx.x * 64, k0 = blockIdx.y * 64;
    const float* W; int ld, cb;
    if (n0 < c1)      { W = w0; ld = ld0; cb = 0;  }
    else if (n0 < c2) { W = w1; ld = ld1; cb = c1; }
    else              { W = w2; ld = ld2; cb = c2; }
    const int tr = threadIdx.x >> 4, tc = threadIdx.x & 15;
    #pragma unroll
    for (int i = 0; i < 4; ++i) {
        int row = tr * 4 + i;  // k-row
        float4 v = *(const float4*)&W[(size_t)(k0 + row) * ld + (n0 - cb) + tc * 4];
        t[row][tc*4+0] = v.x; t[row][tc*4+1] = v.y;
        t[row][tc*4+2] = v.z; t[row][tc*4+3] = v.w;
    }
    __syncthreads();
    #pragma unroll
    for (int i = 0; i < 4; ++i) {
        int nrow = tr * 4 + i;
        union { ushort4 u; f16 h[4]; } o;
        o.h[0] = (f16)t[tc*4+0][nrow]; o.h[1] = (f16)t[tc*4+1][nrow];
        o.h[2] = (f16)t[tc*4+2][nrow]; o.h[3] = (f16)t[tc*4+3][nrow];
        *(ushort4*)&out[(size_t)(n0 + nrow) * 2048 + k0 + tc * 4] = o.u;
    }
}

// ---------------------------------------------------------------------------
// fp16 MFMA GEMM: C[M x N] = A[M x 2048] @ W, W given as Wt[n][k] fp16.
// 128x128 tile, BK=64, 256 thr = 4 waves; wave w: rows w*32..+32, all 128 cols.
// LDS tiles [128][64] f16, granule(16B) XOR-swizzled by (row&7) -> conflict-free
// ds_read_b128 fragment loads. Staging via global_load_lds w/ pre-swizzled src.
// MODE 1: fused QKV epilogue (q:rope+scale fp16, k:rope fp16, v: transposed fp16)
// MODE 0: plain fp32 store.
// ---------------------------------------------------------------------------
template<int MODE>
__global__ __launch_bounds__(256, 2)
void gemm16(const f16* __restrict__ A, const f16* __restrict__ Bt,
            const float* __restrict__ cosp, const float* __restrict__ sinp,
            f16* __restrict__ Oq, f16* __restrict__ Ok, f16* __restrict__ Ov,
            float* __restrict__ Of)
{
    __shared__ f16 As[128 * 64];
    __shared__ f16 Bs[128 * 64];
    const int tid   = threadIdx.x;
    const int lane  = tid & 63;
    const int wid   = tid >> 6;
    const int col_l = lane & 15;
    const int hi    = lane >> 4;
    const int m0 = blockIdx.y * 128;
    const int n0 = blockIdx.x * 128;

    f32x4 acc[2][8];
    #pragma unroll
    for (int mt = 0; mt < 2; ++mt)
        #pragma unroll
        for (int nt = 0; nt < 8; ++nt)
            acc[mt][nt] = (f32x4){0.f, 0.f, 0.f, 0.f};

    for (int kt = 0; kt < 32; ++kt) {
        __syncthreads();
        #pragma unroll
        for (int j = 0; j < 4; ++j) {
            int gidx = j * 256 + tid;
            int r = gidx >> 3, g = gidx & 7;
            int gs = (g ^ (r & 7)) << 3;      // pre-swizzled source granule
            glds16(A  + (size_t)(m0 + r) * 2048 + kt * 64 + gs,
                   (char*)As + (size_t)(j * 256 + (wid << 6)) * 16);
            glds16(Bt + (size_t)(n0 + r) * 2048 + kt * 64 + gs,
                   (char*)Bs + (size_t)(j * 256 + (wid << 6)) * 16);
        }
        asm volatile("s_waitcnt vmcnt(0)" ::: "memory");
        __syncthreads();

        #pragma unroll
        for (int ks = 0; ks < 2; ++ks) {
            int gr = (ks << 2) | hi;
            int ar0 = wid * 32 + col_l;
            int ar1 = ar0 + 16;
            f16x8 a0 = *(const f16x8*)&As[ar0 * 64 + ((gr ^ (ar0 & 7)) << 3)];
            f16x8 a1 = *(const f16x8*)&As[ar1 * 64 + ((gr ^ (ar1 & 7)) << 3)];
            #pragma unroll
            for (int nt = 0; nt < 8; ++nt) {
                int br = nt * 16 + col_l;
                f16x8 b = *(const f16x8*)&Bs[br * 64 + ((gr ^ (br & 7)) << 3)];
                acc[0][nt] = mfma16(a0, b, acc[0][nt]);
                acc[1][nt] = mfma16(a1, b, acc[1][nt]);
            }
        }
    }

    // ---- epilogue ----  C row = m0 + wid*32 + mt*16 + hi*4 + r ; col = n0 + nt*16 + col_l
    if (MODE == 0) {
        #pragma unroll
        for (int mt = 0; mt < 2; ++mt)
            #pragma unroll
            for (int r = 0; r < 4; ++r) {
                int grow = m0 + wid * 32 + mt * 16 + hi * 4 + r;
                #pragma unroll
                for (int nt = 0; nt < 8; ++nt)
                    Of[(size_t)grow * 2048 + n0 + nt * 16 + col_l] = acc[mt][nt][r];
            }
    } else if (n0 < 2048) {            // q: rope + scale
        #pragma unroll
        for (int mt = 0; mt < 2; ++mt)
            #pragma unroll
            for (int r = 0; r < 4; ++r) {
                int grow = m0 + wid * 32 + mt * 16 + hi * 4 + r;
                int srow = grow & (SEQ - 1);
                #pragma unroll
                for (int nt = 0; nt < 4; ++nt) {
                    int d = nt * 16 + col_l;          // 0..63 (head-aligned tile)
                    float lo = acc[mt][nt][r], hv = acc[mt][nt + 4][r];
                    float cl = cosp[srow * HEAD + d],      sl = sinp[srow * HEAD + d];
                    float ch = cosp[srow * HEAD + d + 64], sh = sinp[srow * HEAD + d + 64];
                    Oq[(size_t)grow * 2048 + n0 + d]      = (f16)((lo * cl - hv * sl) * QSC);
                    Oq[(size_t)grow * 2048 + n0 + d + 64] = (f16)((hv * ch + lo * sh) * QSC);
                }
            }
    } else if (n0 < 2560) {            // k: rope
        #pragma unroll
        for (int mt = 0; mt < 2; ++mt)
            #pragma unroll
            for (int r = 0; r < 4; ++r) {
                int grow = m0 + wid * 32 + mt * 16 + hi * 4 + r;
                int srow = grow & (SEQ - 1);
                #pragma unroll
                for (int nt = 0; nt < 4; ++nt) {
                    int kc = (n0 - 2048) + nt * 16 + col_l;
                    int d  = kc & 127;                 // 0..63
                    float lo = acc[mt][nt][r], hv = acc[mt][nt + 4][r];
                    float cl = cosp[srow * HEAD + d],      sl = sinp[srow * HEAD + d];
                    float ch = cosp[srow * HEAD + d + 64], sh = sinp[srow * HEAD + d + 64];
                    Ok[(size_t)grow * 512 + kc]      = (f16)(lo * cl - hv * sl);
                    Ok[(size_t)grow * 512 + kc + 64] = (f16)(hv * ch + lo * sh);
                }
            }
    } else {                           // v: write transposed vT[(b*4+kv)*128+d][1024]
        #pragma unroll
        for (int mt = 0; mt < 2; ++mt) {
            int grow0 = m0 + wid * 32 + mt * 16 + hi * 4;
            int bb = grow0 >> 10, s0 = grow0 & (SEQ - 1);
            #pragma unroll
            for (int nt = 0; nt < 8; ++nt) {
                int vcol = (n0 - 2560) + nt * 16 + col_l;
                int kvh = vcol >> 7, d = vcol & 127;
                union { ushort4 u; f16 h[4]; } pv;
                #pragma unroll
                for (int r = 0; r < 4; ++r) pv.h[r] = (f16)acc[mt][nt][r];
                *(ushort4*)&Ov[(size_t)((bb * 4 + kvh) * 128 + d) * 1024 + s0] = pv.u;
            }
        }
    }
}

// ---------------------------------------------------------------------------
// MFMA flash attention (causal, GQA). fp16 inputs, fp32 accumulate.
// 256 thr = 4 waves; block = (b,h, 64 q-rows), wave = 16 q-rows.
// Swapped QK^T: S^T = mfma(K, Q) so lane holds 8 scores of q-row (lane&15):
//   k = kt*32 + t*16 + (lane>>4)*4 + reg   (slot = t*4+reg)
// softmax row-reduce = 8-reg chain + shfl_xor(16,32).
// P repack to A-fragment layout (q=lane&15, k=(lane>>4)*8+e) via
// cvt_pkrtz + 8 ds_bpermute + 4 selects. PV B-operand from transposed-V LDS.
// ---------------------------------------------------------------------------
__global__ __launch_bounds__(256, 2)
void attn16(const f16* __restrict__ q16, const f16* __restrict__ k16,
            const f16* __restrict__ vT, f16* __restrict__ attnb)
{
    __shared__ f16 Ks[32 * 128];   // [k-row 32][d 128], granule^(r&7) swizzle
    __shared__ f16 Vs[128 * 32];   // [d 128][k 32],      granule^(d&3) swizzle

    const int tid   = threadIdx.x;
    const int lane  = tid & 63;
    const int wid   = tid >> 6;
    const int col_l = lane & 15;   // q for S^T, d-col for O
    const int hi    = lane >> 4;

    const int bx = blockIdx.x;
    const int qt = 15 - (bx >> 5);         // heavy tiles first
    const int bh = bx & 31;
    const int b  = bh >> 4;
    const int h  = bh & 15;
    const int kv = h >> 2;
    const int qrow = qt * 64 + wid * 16 + col_l;     // this lane's q (S^T view)

    // Q fragments in registers (already roped+scaled fp16)
    f16x8 qf[4];
    {
        const f16* qp = q16 + (size_t)(b * SEQ + qrow) * 2048 + h * 128 + hi * 8;
        #pragma unroll
        for (int ks = 0; ks < 4; ++ks) qf[ks] = *(const f16x8*)&qp[ks * 32];
    }
    const f16* vTg = vT + (size_t)(b * 4 + kv) * 128 * 1024;

    f32x4 O[8];
    #pragma unroll
    for (int dt = 0; dt < 8; ++dt) O[dt] = (f32x4){0.f, 0.f, 0.f, 0.f};
    float mrun = -INFINITY, lrun = 0.f;

    const int ntiles = 2 * (qt + 1);
    for (int kt = 0; kt < ntiles; ++kt) {
        __syncthreads();
        #pragma unroll
        for (int j = 0; j < 2; ++j) {
            int gidx = j * 256 + tid;
            int r = gidx >> 4, g = gidx & 15;      // K tile granule
            glds16(k16 + (size_t)(b * SEQ + kt * 32 + r) * 512 + kv * 128 + ((g ^ (r & 7)) << 3),
                   (char*)Ks + (size_t)(j * 256 + (wid << 6)) * 16);
            int d = gidx >> 2, g2 = gidx & 3;      // Vt tile granule
            glds16(vTg + (size_t)d * 1024 + kt * 32 + ((g2 ^ (d & 3)) << 3),
                   (char*)Vs + (size_t)(j * 256 + (wid << 6)) * 16);
        }
        asm volatile("s_waitcnt vmcnt(0)" ::: "memory");
        __syncthreads();

        // ---- S^T = K . Q^T  (two 16-row k-subtiles) ----
        f32x4 S0 = (f32x4){0.f,0.f,0.f,0.f}, S1 = (f32x4){0.f,0.f,0.f,0.f};
        #pragma unroll
        for (int ks = 0; ks < 4; ++ks) {
            int gr = (ks << 2) | hi;
            int r0 = col_l, r1 = col_l + 16;
            f16x8 kf0 = *(const f16x8*)&Ks[r0 * 128 + ((gr ^ (r0 & 7)) << 3)];
            f16x8 kf1 = *(const f16x8*)&Ks[r1 * 128 + ((gr ^ (r1 & 7)) << 3)];
            S0 = mfma16(kf0, qf[ks], S0);
            S1 = mfma16(kf1, qf[ks], S1);
        }
        float p[8];
        p[0]=S0[0]; p[1]=S0[1]; p[2]=S0[2]; p[3]=S0[3];
        p[4]=S1[0]; p[5]=S1[1]; p[6]=S1[2]; p[7]=S1[3];

        // causal mask: k index of slot = kt*32 + (sl>>2)*16 + hi*4 + (sl&3)
        #pragma unroll
        for (int sl = 0; sl < 8; ++sl) {
            int kk = kt * 32 + (sl >> 2) * 16 + hi * 4 + (sl & 3);
            if (kk > qrow) p[sl] = -INFINITY;
        }

        // ---- online softmax (per q-row, replicated across hi groups) ----
        float mt = p[0];
        #pragma unroll
        for (int sl = 1; sl < 8; ++sl) mt = fmaxf(mt, p[sl]);
        mt = fmaxf(mt, __shfl_xor(mt, 16));
        mt = fmaxf(mt, __shfl_xor(mt, 32));
        float mnew = fmaxf(mrun, mt);
        float corr = __expf(mrun - mnew);
        mrun = mnew;
        float ps = 0.f;
        #pragma unroll
        for (int sl = 0; sl < 8; ++sl) { p[sl] = __expf(p[sl] - mnew); ps += p[sl]; }
        ps += __shfl_xor(ps, 16);
        ps += __shfl_xor(ps, 32);
        lrun = lrun * corr + ps;

        // ---- repack P into A-fragment layout (q=lane&15, k=(lane>>4)*8+e) ----
        union U2 { h16x2 h; int i; };
        int pk[4];
        { U2 u; u.h = __builtin_amdgcn_cvt_pkrtz(p[0], p[1]); pk[0] = u.i; }
        { U2 u; u.h = __builtin_amdgcn_cvt_pkrtz(p[2], p[3]); pk[1] = u.i; }
        { U2 u; u.h = __builtin_amdgcn_cvt_pkrtz(p[4], p[5]); pk[2] = u.i; }
        { U2 u; u.h = __builtin_amdgcn_cvt_pkrtz(p[6], p[7]); pk[3] = u.i; }
        union UA { f16x8 v; int i[4]; } ua;
        #pragma unroll
        for (int j = 0; j < 4; ++j) {
            int srcl = col_l + 16 * ((2 * hi + (j >> 1)) & 3);
            int v0 = __builtin_amdgcn_ds_bpermute(srcl << 2, pk[j & 1]);
            int v1 = __builtin_amdgcn_ds_bpermute(srcl << 2, pk[(j & 1) + 2]);
            ua.i[j] = (hi >= 2) ? v1 : v0;
        }

        // ---- rescale O (corr broadcast to acc-row layout q' = hi*4+r) ----
        float cb[4];
        #pragma unroll
        for (int r = 0; r < 4; ++r)
            cb[r] = __int_as_float(__builtin_amdgcn_ds_bpermute((hi * 4 + r) << 2,
                                                                __float_as_int(corr)));
        #pragma unroll
        for (int dt = 0; dt < 8; ++dt) {
            O[dt][0] *= cb[0]; O[dt][1] *= cb[1];
            O[dt][2] *= cb[2]; O[dt][3] *= cb[3];
        }

        // ---- O += P @ V ----
        #pragma unroll
        for (int dt = 0; dt < 8; ++dt) {
            int vr = dt * 16 + col_l;
            f16x8 vf = *(const f16x8*)&Vs[vr * 32 + (((hi) ^ (vr & 3)) << 3)];
            O[dt] = mfma16(ua.v, vf, O[dt]);
        }
    }

    // ---- finalize: divide by l (broadcast to acc-row layout) and store fp16 ----
    float linv = 1.f / lrun;
    float lb[4];
    #pragma unroll
    for (int r = 0; r < 4; ++r)
        lb[r] = __int_as_float(__builtin_amdgcn_ds_bpermute((hi * 4 + r) << 2,
                                                            __float_as_int(linv)));
    #pragma unroll
    for (int dt = 0; dt < 8; ++dt)
        #pragma unroll
        for (int r = 0; r < 4; ++r) {
            int row = b * SEQ + qt * 64 + wid * 16 + hi * 4 + r;
            attnb[(size_t)row * 2048 + h * 128 + dt * 16 + col_l] = (f16)(O[dt][r] * lb[r]);
        }
}

// ---------------------------------------------------------------------------
extern "C" void kernel_launch(void* const* d_in, const int* in_sizes, int n_in,
                              void* d_out, int out_size, void* d_ws, size_t ws_size,
                              hipStream_t stream)
{
    const float* x    = (const float*)d_in[0];
    const float* cosp = (const float*)d_in[1];
    const float* sinp = (const float*)d_in[2];
    const float* wq   = (const float*)d_in[3];
    const float* wk   = (const float*)d_in[4];
    const float* wv   = (const float*)d_in[5];
    const float* wo   = (const float*)d_in[6];
    float* out = (float*)d_out;

    // workspace layout (32 MiB total):
    //   [0,        8388608)  x16      (fp16 x)          -> reused as attn16 after GEMM1
    //   [8388608, 20971520)  Wqkvt    (fp16 [3072][2048]) -> reused as Wot after GEMM1
    //   [20971520,29360128)  q16      (fp16 [2048][2048], roped+scaled)
    //   [29360128,31457280)  k16      (fp16 [2048][512],  roped)
    //   [31457280,33554432)  vT       (fp16 [(b*4+kv)*128+d][1024])
    char* ws = (char*)d_ws;
    f16* x16    = (f16*)(ws);
    f16* attn16v= (f16*)(ws);                 // overlay (x dead after GEMM1)
    f16* Wqkvt  = (f16*)(ws + 8388608);
    f16* Wot    = (f16*)(ws + 8388608);       // overlay (Wqkvt dead after GEMM1)
    f16* q16    = (f16*)(ws + 20971520);
    f16* k16    = (f16*)(ws + 29360128);
    f16* vT     = (f16*)(ws + 31457280);

    // 1. x fp32 -> fp16   (4M elems, 4/thread)
    cvt_f32_f16<<<4096, 256, 0, stream>>>(x, x16);

    // 2. transpose+convert Wqkv -> Wqkvt [3072][2048]
    transW<<<dim3(48, 32), 256, 0, stream>>>(wq, wk, wv, Wqkvt, 2048, 2560, 2048, 512, 512);

    // 3. fused QKV projection + RoPE (writes q16, k16, vT)
    gemm16<1><<<dim3(24, 16), 256, 0, stream>>>(x16, Wqkvt, cosp, sinp,
                                                q16, k16, vT, nullptr);

    // 4. transpose+convert wo -> Wot [2048][2048]
    transW<<<dim3(32, 32), 256, 0, stream>>>(wo, wo, wo, Wot, 2048, 2048, 2048, 2048, 2048);

    // 5. causal GQA MFMA flash attention -> attn16 (fp16, overlays x16)
    attn16<<<dim3(512), 256, 0, stream>>>(q16, k16, vT, attn16v);

    // 6. output projection (fp32 out)
    gemm16<0><<<dim3(16, 16), 256, 0, stream>>>(attn16v, Wot, nullptr, nullptr,
                                                nullptr, nullptr, nullptr, out);
}